// Round 20
// baseline (179.143 us; speedup 1.0000x reference)
//
#include <hip/hip_runtime.h>

#define NHID 256
#define NFEAT 512

using short8  = __attribute__((ext_vector_type(8))) short;
using float8  = __attribute__((ext_vector_type(8))) float;
using f32x4   = __attribute__((ext_vector_type(4))) float;

__device__ __forceinline__ float b2f(unsigned short u) {
    union { float f; unsigned v; } c;
    c.v = ((unsigned)u) << 16;
    return c.f;
}
__device__ __forceinline__ unsigned short f2b(float f) {
    union { float f; unsigned u; } c;
    c.f = f;
    unsigned r = c.u + 0x7fffu + ((c.u >> 16) & 1u);  // RNE
    return (unsigned short)(r >> 16);
}
__device__ __forceinline__ unsigned short f2h(float f) {
    union { _Float16 h; unsigned short u; } c;
    c.h = (_Float16)f;
    return c.u;
}
__device__ __forceinline__ float h2f(unsigned short u) {
    union { _Float16 h; unsigned short u; } c;
    c.u = u;
    return (float)c.h;
}

// async global->LDS, 16 B/lane; lds base wave-uniform, gsrc per-lane.
__device__ __forceinline__ void gload16(const void* gsrc, void* lds) {
    __builtin_amdgcn_global_load_lds((const __attribute__((address_space(1))) unsigned int*)gsrc,
                                     (__attribute__((address_space(3))) unsigned int*)lds,
                                     16, 0, 0);
}

// ---------------- prep: W1 -> MFMA frags, WP = W2 @ [Wlin_top|Wlin_bot], cursor zero ----------------
__global__ __launch_bounds__(256) void prep_all(const float* __restrict__ W1,
                                                const float* __restrict__ W2,
                                                const float* __restrict__ Wlin,
                                                unsigned short* __restrict__ F1,
                                                float* __restrict__ WP,
                                                int* __restrict__ cursor, int M) {
    int i = blockIdx.x * blockDim.x + threadIdx.x;
    const int T1 = NFEAT * NHID;   // 131072
    if (i < T1) {
        int j = i & 7, l = (i >> 3) & 63, cb = (i >> 9) & 15, t = i >> 13;
        int n = cb * 16 + (l & 15);
        int k = t * 32 + ((l >> 4) << 3) + j;
        F1[i] = f2b(W1[k * NHID + n]);
    } else if (i < T1 + NHID * 4) {
        int i3 = i - T1;
        int k = i3 >> 2, j = i3 & 3;
        const int base = (j >= 2) ? NHID : 0;
        const int col = j & 1;
        float acc = 0.f;
        for (int n = 0; n < NHID; ++n)
            acc += W2[k * NHID + n] * Wlin[(base + n) * 2 + col];
        WP[k * 4 + j] = acc;
    } else {
        int j = i - T1 - NHID * 4;
        if (j < M) cursor[j] = 0;
    }
}

// ---------------- GEMM1 body (round-14 verified): fp32 A via gload+swizzle, B frag regs ----------------
__device__ __forceinline__ void gemm1_body(const float* __restrict__ x,
                                           const unsigned short* __restrict__ F1,
                                           unsigned short* __restrict__ C, int M,
                                           int brow, char* AsRaw /* 2*8192 */) {
    const int tid = threadIdx.x;
    const int lane = tid & 63;
    const int wc = tid >> 6;
    const int lrow = lane & 15;
    const int lq = lane >> 4;
    const int nt = NFEAT / 32;   // 16

    int ar0 = brow + wc * 16 + (lane >> 3);
    int ar1 = ar0 + 8;
    if (ar0 >= M) ar0 = M - 1;
    if (ar1 >= M) ar1 = M - 1;
    const int aswz = ((lane & 7) ^ (lane >> 3)) * 4;
    const float* ag0 = x + (size_t)ar0 * NFEAT + aswz;
    const float* ag1 = x + (size_t)ar1 * NFEAT + aswz;
    const unsigned short* bsrc = F1 + (wc * 4) * 512 + lane * 8;

    f32x4 acc[4][4] = {};

    gload16(ag0, AsRaw + wc * 2048);
    gload16(ag1, AsRaw + wc * 2048 + 1024);
    short8 bc0 = *(const short8*)(bsrc + 0 * 512);
    short8 bc1 = *(const short8*)(bsrc + 1 * 512);
    short8 bc2 = *(const short8*)(bsrc + 2 * 512);
    short8 bc3 = *(const short8*)(bsrc + 3 * 512);
    __syncthreads();

    int p = 0;
#pragma unroll
    for (int t = 0; t < 16; ++t) {
        short8 bn0, bn1, bn2, bn3;
        if (t + 1 < nt) {
            gload16(ag0 + (t + 1) * 32, AsRaw + (p ^ 1) * 8192 + wc * 2048);
            gload16(ag1 + (t + 1) * 32, AsRaw + (p ^ 1) * 8192 + wc * 2048 + 1024);
            const unsigned short* bs_ = bsrc + (t + 1) * 8192;
            bn0 = *(const short8*)(bs_ + 0 * 512);
            bn1 = *(const short8*)(bs_ + 1 * 512);
            bn2 = *(const short8*)(bs_ + 2 * 512);
            bn3 = *(const short8*)(bs_ + 3 * 512);
        }
        short8 a[4];
#pragma unroll
        for (int m = 0; m < 4; ++m) {
            int row = m * 16 + lrow;
            const char* base = AsRaw + p * 8192 + row * 128;
            int sw = (row & 7) << 4;
            float4 f0 = *(const float4*)(base + ((lq * 32) ^ sw));
            float4 f1 = *(const float4*)(base + ((lq * 32 + 16) ^ sw));
            short8 v;
            v[0] = (short)f2b(f0.x); v[1] = (short)f2b(f0.y);
            v[2] = (short)f2b(f0.z); v[3] = (short)f2b(f0.w);
            v[4] = (short)f2b(f1.x); v[5] = (short)f2b(f1.y);
            v[6] = (short)f2b(f1.z); v[7] = (short)f2b(f1.w);
            a[m] = v;
        }
#pragma unroll
        for (int m = 0; m < 4; ++m) {
            acc[m][0] = __builtin_amdgcn_mfma_f32_16x16x32_bf16(a[m], bc0, acc[m][0], 0, 0, 0);
            acc[m][1] = __builtin_amdgcn_mfma_f32_16x16x32_bf16(a[m], bc1, acc[m][1], 0, 0, 0);
            acc[m][2] = __builtin_amdgcn_mfma_f32_16x16x32_bf16(a[m], bc2, acc[m][2], 0, 0, 0);
            acc[m][3] = __builtin_amdgcn_mfma_f32_16x16x32_bf16(a[m], bc3, acc[m][3], 0, 0, 0);
        }
        __syncthreads();
        p ^= 1;
        bc0 = bn0; bc1 = bn1; bc2 = bn2; bc3 = bn3;
    }

#pragma unroll
    for (int m = 0; m < 4; ++m)
#pragma unroll
        for (int r = 0; r < 4; ++r) {
            int row = brow + m * 16 + (lane >> 4) * 4 + r;
            if (row < M) {
#pragma unroll
                for (int n = 0; n < 4; ++n) {
                    int col = wc * 64 + n * 16 + (lane & 15);
                    C[(size_t)row * NHID + col] = f2b(acc[m][n][r]);
                }
            }
        }
}

// ---------------- K2: gemm1 (first half rows) + hist_rank ----------------
__global__ __launch_bounds__(256) void fused_g1_histrank(const float* __restrict__ x,
                                                         const unsigned short* __restrict__ F1,
                                                         unsigned short* __restrict__ C, int M,
                                                         int gblocks,
                                                         const int* __restrict__ dst,
                                                         int* __restrict__ counts,
                                                         int* __restrict__ rank, int E) {
    __shared__ char AsRaw[2 * 8192];
    if ((int)blockIdx.x < gblocks) {
        gemm1_body(x, F1, C, M, blockIdx.x * 64, AsRaw);
    } else {
        const int rank_b = blockIdx.x - gblocks;
        const int nrank = gridDim.x - gblocks;
        for (int e = rank_b * blockDim.x + threadIdx.x; e < E; e += nrank * blockDim.x)
            rank[e] = atomicAdd(&counts[dst[e]], 1);
    }
}

// ---------------- K6: gemm1 (second half rows) + rank_sort (no atomics) ----------------
__global__ __launch_bounds__(256) void fused_g1_ranksort(const float* __restrict__ x,
                                                         const unsigned short* __restrict__ F1,
                                                         unsigned short* __restrict__ C, int M,
                                                         int gblocks, int rowbase,
                                                         const int* __restrict__ src,
                                                         const int* __restrict__ dst,
                                                         const float* __restrict__ w,
                                                         const int* __restrict__ offsets,
                                                         const int* __restrict__ rank,
                                                         unsigned* __restrict__ pk,
                                                         int E, int span) {
    __shared__ char AsRaw[2 * 8192];
    if ((int)blockIdx.x < gblocks) {
        gemm1_body(x, F1, C, M, (rowbase + blockIdx.x) * 64, AsRaw);
    } else {
        const int rb = blockIdx.x - gblocks;
        const int nrb = gridDim.x - gblocks;
        const int g = rb & 7;
        const int r8 = rb >> 3;
        const int n8 = nrb >> 3;
        const int lo = g * span;
        const int hi = min(lo + span, M);
        for (int e = r8 * blockDim.x + threadIdx.x; e < E; e += n8 * blockDim.x) {
            int d = dst[e];
            if (d >= lo && d < hi)
                pk[offsets[d] + rank[e]] = ((unsigned)f2h(w[e]) << 16) | (unsigned)src[e];
        }
    }
}

// ---------------- scan: per-block local scan + fused (sums+finalize) ----------------
__global__ __launch_bounds__(1024) void scan_local(const int* __restrict__ counts,
                                                   int* __restrict__ local,
                                                   int* __restrict__ blocksums, int n) {
    __shared__ int s[1024];
    const int tid = threadIdx.x;
    const int idx = blockIdx.x * 1024 + tid;
    int v = (idx < n) ? counts[idx] : 0;
    s[tid] = v;
    __syncthreads();
    for (int off = 1; off < 1024; off <<= 1) {
        int t = (tid >= off) ? s[tid - off] : 0;
        __syncthreads();
        s[tid] += t;
        __syncthreads();
    }
    if (idx < n) local[idx] = s[tid] - v;
    if (tid == 1023) blocksums[blockIdx.x] = s[1023];
}

__global__ __launch_bounds__(256) void scan_fin2(int* __restrict__ offsets,
                                                 const int* __restrict__ blocksums,
                                                 int nb, int n, int total) {
    __shared__ int s[64];
    const int tid = threadIdx.x;
    if (tid < 64) s[tid] = (tid < nb) ? blocksums[tid] : 0;
    __syncthreads();
    int idx = blockIdx.x * blockDim.x + tid;
    if (idx < n) {
        int grp = idx >> 10;
        int gsum = 0;
        for (int j = 0; j < grp; ++j) gsum += s[j];
        offsets[idx] += gsum;
    }
    if (idx == 0) offsets[n] = total;
}

// ---------------- gather1 + relu + WP projection (8-deep ILP) ----------------
__global__ __launch_bounds__(256) void gather1_proj(const unsigned short* __restrict__ h,
                                                    const int* __restrict__ offsets,
                                                    const unsigned* __restrict__ pk,
                                                    const float* __restrict__ WP,
                                                    float4* __restrict__ y4, int N) {
    const int lane = threadIdx.x & 63;
    const int wid = threadIdx.x >> 6;
    const int node = blockIdx.x * 4 + wid;
    if (node >= N) return;

    float wp[4][4];
#pragma unroll
    for (int i = 0; i < 4; ++i) {
        float4 r = ((const float4*)WP)[lane * 4 + i];
        wp[i][0] = r.x; wp[i][1] = r.y; wp[i][2] = r.z; wp[i][3] = r.w;
    }

    const int s0 = offsets[node];
    const int s1 = offsets[node + 1];
    float a0 = 0.f, a1 = 0.f, a2 = 0.f, a3 = 0.f;
    int i = s0;
    // 8-deep: 8 independent row gathers in flight
    for (; i + 8 <= s1; i += 8) {
        unsigned q0 = pk[i],     q1 = pk[i + 1], q2 = pk[i + 2], q3 = pk[i + 3];
        unsigned q4 = pk[i + 4], q5 = pk[i + 5], q6 = pk[i + 6], q7 = pk[i + 7];
        ushort4 v0 = ((const ushort4*)(h + (size_t)(q0 & 0xffffu) * NHID))[lane];
        ushort4 v1 = ((const ushort4*)(h + (size_t)(q1 & 0xffffu) * NHID))[lane];
        ushort4 v2 = ((const ushort4*)(h + (size_t)(q2 & 0xffffu) * NHID))[lane];
        ushort4 v3 = ((const ushort4*)(h + (size_t)(q3 & 0xffffu) * NHID))[lane];
        ushort4 v4 = ((const ushort4*)(h + (size_t)(q4 & 0xffffu) * NHID))[lane];
        ushort4 v5 = ((const ushort4*)(h + (size_t)(q5 & 0xffffu) * NHID))[lane];
        ushort4 v6 = ((const ushort4*)(h + (size_t)(q6 & 0xffffu) * NHID))[lane];
        ushort4 v7 = ((const ushort4*)(h + (size_t)(q7 & 0xffffu) * NHID))[lane];
        float w0 = h2f(q0 >> 16), w1 = h2f(q1 >> 16), w2 = h2f(q2 >> 16), w3 = h2f(q3 >> 16);
        float w4 = h2f(q4 >> 16), w5 = h2f(q5 >> 16), w6 = h2f(q6 >> 16), w7 = h2f(q7 >> 16);
        a0 += w0 * b2f(v0.x) + w1 * b2f(v1.x) + w2 * b2f(v2.x) + w3 * b2f(v3.x)
            + w4 * b2f(v4.x) + w5 * b2f(v5.x) + w6 * b2f(v6.x) + w7 * b2f(v7.x);
        a1 += w0 * b2f(v0.y) + w1 * b2f(v1.y) + w2 * b2f(v2.y) + w3 * b2f(v3.y)
            + w4 * b2f(v4.y) + w5 * b2f(v5.y) + w6 * b2f(v6.y) + w7 * b2f(v7.y);
        a2 += w0 * b2f(v0.z) + w1 * b2f(v1.z) + w2 * b2f(v2.z) + w3 * b2f(v3.z)
            + w4 * b2f(v4.z) + w5 * b2f(v5.z) + w6 * b2f(v6.z) + w7 * b2f(v7.z);
        a3 += w0 * b2f(v0.w) + w1 * b2f(v1.w) + w2 * b2f(v2.w) + w3 * b2f(v3.w)
            + w4 * b2f(v4.w) + w5 * b2f(v5.w) + w6 * b2f(v6.w) + w7 * b2f(v7.w);
    }
    for (; i + 4 <= s1; i += 4) {
        unsigned q0 = pk[i], q1 = pk[i + 1], q2 = pk[i + 2], q3 = pk[i + 3];
        ushort4 v0 = ((const ushort4*)(h + (size_t)(q0 & 0xffffu) * NHID))[lane];
        ushort4 v1 = ((const ushort4*)(h + (size_t)(q1 & 0xffffu) * NHID))[lane];
        ushort4 v2 = ((const ushort4*)(h + (size_t)(q2 & 0xffffu) * NHID))[lane];
        ushort4 v3 = ((const ushort4*)(h + (size_t)(q3 & 0xffffu) * NHID))[lane];
        float w0 = h2f(q0 >> 16), w1 = h2f(q1 >> 16), w2 = h2f(q2 >> 16), w3 = h2f(q3 >> 16);
        a0 += w0 * b2f(v0.x) + w1 * b2f(v1.x) + w2 * b2f(v2.x) + w3 * b2f(v3.x);
        a1 += w0 * b2f(v0.y) + w1 * b2f(v1.y) + w2 * b2f(v2.y) + w3 * b2f(v3.y);
        a2 += w0 * b2f(v0.z) + w1 * b2f(v1.z) + w2 * b2f(v2.z) + w3 * b2f(v3.z);
        a3 += w0 * b2f(v0.w) + w1 * b2f(v1.w) + w2 * b2f(v2.w) + w3 * b2f(v3.w);
    }
    for (; i < s1; ++i) {
        unsigned q = pk[i];
        float ww = h2f(q >> 16);
        ushort4 v = ((const ushort4*)(h + (size_t)(q & 0xffffu) * NHID))[lane];
        a0 += ww * b2f(v.x);
        a1 += ww * b2f(v.y);
        a2 += ww * b2f(v.z);
        a3 += ww * b2f(v.w);
    }
    a0 = fmaxf(a0, 0.f); a1 = fmaxf(a1, 0.f);
    a2 = fmaxf(a2, 0.f); a3 = fmaxf(a3, 0.f);

    float t0 = a0 * wp[0][0] + a1 * wp[1][0] + a2 * wp[2][0] + a3 * wp[3][0];
    float t1 = a0 * wp[0][1] + a1 * wp[1][1] + a2 * wp[2][1] + a3 * wp[3][1];
    float t2 = a0 * wp[0][2] + a1 * wp[1][2] + a2 * wp[2][2] + a3 * wp[3][2];
    float t3 = a0 * wp[0][3] + a1 * wp[1][3] + a2 * wp[2][3] + a3 * wp[3][3];
#pragma unroll
    for (int off = 32; off > 0; off >>= 1) {
        t0 += __shfl_down(t0, off);
        t1 += __shfl_down(t1, off);
        t2 += __shfl_down(t2, off);
        t3 += __shfl_down(t3, off);
    }
    if (lane == 0) y4[node] = {t0, t1, t2, t3};
}

// ---------------- gather2 (tiny, unchanged) ----------------
__global__ __launch_bounds__(256) void gather2_small(const float4* __restrict__ y4,
                                                     const int* __restrict__ offsets,
                                                     const unsigned* __restrict__ pk,
                                                     float2* __restrict__ za,
                                                     float2* __restrict__ zb, int N) {
    const int lane = threadIdx.x & 63;
    const int wid = threadIdx.x >> 6;
    const int grp = lane >> 4;
    const int slot = lane & 15;
    const int node = blockIdx.x * 16 + wid * 4 + grp;
    if (node >= N) return;

    const int s0 = offsets[node];
    const int s1 = offsets[node + 1];
    float x0 = 0.f, x1 = 0.f, x2 = 0.f, x3 = 0.f;
    for (int i = s0 + slot; i < s1; i += 16) {
        unsigned q = pk[i];
        float ww = h2f(q >> 16);
        float4 v = y4[q & 0xffffu];
        x0 += ww * v.x; x1 += ww * v.y; x2 += ww * v.z; x3 += ww * v.w;
    }
#pragma unroll
    for (int off = 8; off > 0; off >>= 1) {
        x0 += __shfl_xor(x0, off);
        x1 += __shfl_xor(x1, off);
        x2 += __shfl_xor(x2, off);
        x3 += __shfl_xor(x3, off);
    }
    if (slot == 0) {
        za[node] = {x0, x1};
        zb[node] = {x2, x3};
    }
}

// ---------------- Decode (unchanged) ----------------
__global__ __launch_bounds__(256) void decode_pairs(const float2* __restrict__ za,
                                                    const float2* __restrict__ zb,
                                                    const int* __restrict__ ps,
                                                    const int* __restrict__ pd,
                                                    float2* __restrict__ out, int P) {
    int p = blockIdx.x * blockDim.x + threadIdx.x;
    if (p < P) {
        float2 va = za[ps[p]];
        float2 vb = zb[pd[p]];
        out[p] = {va.x + vb.x, va.y + vb.y};
    }
}

// ================= fp32 fallback path (ws too small or M > 65535) =================
template <bool RELU>
__global__ __launch_bounds__(256) void gemm_tiled(const float* __restrict__ A,
                                                  const float* __restrict__ B,
                                                  float* __restrict__ C,
                                                  int M, int N, int K) {
    __shared__ float As[16][65];
    __shared__ float Bs[16][64];
    const int block_row = blockIdx.x * 64;
    const int block_col = blockIdx.y * 64;
    const int tid = threadIdx.x;
    const int tx = tid & 15;
    const int ty = tid >> 4;
    float c[4][4] = {};
    for (int k0 = 0; k0 < K; k0 += 16) {
#pragma unroll
        for (int i = 0; i < 4; ++i) {
            int idx = tid + i * 256;
            int kk = idx & 15;
            int m = idx >> 4;
            int row = block_row + m;
            float v = 0.f;
            if (row < M) v = A[(long)row * K + k0 + kk];
            if (RELU) v = fmaxf(v, 0.f);
            As[kk][m] = v;
        }
#pragma unroll
        for (int i = 0; i < 4; ++i) {
            int idx = tid + i * 256;
            int n = idx & 63;
            int kk = idx >> 6;
            Bs[kk][n] = B[(long)(k0 + kk) * N + block_col + n];
        }
        __syncthreads();
#pragma unroll
        for (int kk = 0; kk < 16; ++kk) {
            float a[4], b[4];
#pragma unroll
            for (int i = 0; i < 4; ++i) a[i] = As[kk][ty * 4 + i];
#pragma unroll
            for (int j = 0; j < 4; ++j) b[j] = Bs[kk][tx * 4 + j];
#pragma unroll
            for (int i = 0; i < 4; ++i)
#pragma unroll
                for (int j = 0; j < 4; ++j) c[i][j] += a[i] * b[j];
        }
        __syncthreads();
    }
#pragma unroll
    for (int i = 0; i < 4; ++i) {
        int row = block_row + ty * 4 + i;
        if (row < M) {
            float* cp = C + (long)row * N + block_col + tx * 4;
#pragma unroll
            for (int j = 0; j < 4; ++j) cp[j] = c[i][j];
        }
    }
}

__global__ __launch_bounds__(256) void scatter_conv(const float* __restrict__ h,
                                                    const int* __restrict__ src,
                                                    const int* __restrict__ dst,
                                                    const float* __restrict__ w,
                                                    float* __restrict__ z, int E) {
    const int lane = threadIdx.x & 63;
    const int wid = threadIdx.x >> 6;
    const int nwaves = (gridDim.x * blockDim.x) >> 6;
    for (int e = blockIdx.x * 4 + wid; e < E; e += nwaves) {
        int s = src[e];
        int d = dst[e];
        float ww = w[e];
        float4 v = ((const float4*)(h + (long)s * NHID))[lane];
        float* zp = z + (long)d * NHID + lane * 4;
        atomicAdd(zp + 0, ww * v.x);
        atomicAdd(zp + 1, ww * v.y);
        atomicAdd(zp + 2, ww * v.z);
        atomicAdd(zp + 3, ww * v.w);
    }
}

__global__ __launch_bounds__(256) void decode_f(const float* __restrict__ z,
                                                const int* __restrict__ ps,
                                                const int* __restrict__ pd,
                                                const float* __restrict__ Wlin,
                                                float* __restrict__ out, int P) {
    const int lane = threadIdx.x & 63;
    const int wid = threadIdx.x >> 6;
    const int nwaves = (gridDim.x * blockDim.x) >> 6;
    float wa[8], wb[8];
#pragma unroll
    for (int i = 0; i < 8; ++i) {
        wa[i] = Wlin[(lane * 4) * 2 + i];
        wb[i] = Wlin[(NHID + lane * 4) * 2 + i];
    }
    for (int p = blockIdx.x * 4 + wid; p < P; p += nwaves) {
        int a = ps[p];
        int b = pd[p];
        float4 va = ((const float4*)(z + (long)a * NHID))[lane];
        float4 vb = ((const float4*)(z + (long)b * NHID))[lane];
        float acc0 = va.x * wa[0] + va.y * wa[2] + va.z * wa[4] + va.w * wa[6]
                   + vb.x * wb[0] + vb.y * wb[2] + vb.z * wb[4] + vb.w * wb[6];
        float acc1 = va.x * wa[1] + va.y * wa[3] + va.z * wa[5] + va.w * wa[7]
                   + vb.x * wb[1] + vb.y * wb[3] + vb.z * wb[5] + vb.w * wb[7];
#pragma unroll
        for (int off = 32; off > 0; off >>= 1) {
            acc0 += __shfl_down(acc0, off);
            acc1 += __shfl_down(acc1, off);
        }
        if (lane == 0) {
            out[(long)p * 2 + 0] = acc0;
            out[(long)p * 2 + 1] = acc1;
        }
    }
}

extern "C" void kernel_launch(void* const* d_in, const int* in_sizes, int n_in,
                              void* d_out, int out_size, void* d_ws, size_t ws_size,
                              hipStream_t stream) {
    (void)n_in; (void)out_size;
    const float* x    = (const float*)d_in[0];   // [M, 512]
    const int*   ei   = (const int*)d_in[1];     // [2, E]
    const float* ew   = (const float*)d_in[2];   // [E]
    const int*   pei  = (const int*)d_in[3];     // [2, P]
    const float* W1   = (const float*)d_in[4];   // [512, 256]
    const float* W2   = (const float*)d_in[5];   // [256, 256]
    const float* Wlin = (const float*)d_in[6];   // [512, 2]
    float* out = (float*)d_out;                  // [P, 2]

    const int E = in_sizes[2];
    const int P = in_sizes[3] / 2;
    const int M = in_sizes[0] / NFEAT;

    dim3 blk(256);
    const int* src = ei;
    const int* dst = ei + E;

    // workspace layout
    unsigned short* hA = (unsigned short*)d_ws;               // [M,256] bf16 (h1)
    unsigned short* hB = hA + (size_t)M * NHID;               // reused as y4 [M] float4
    int* offsets = (int*)(hB + (size_t)M * NHID);             // [M+1]
    int* cursor  = offsets + (M + 1);                          // [M] (counts)
    unsigned* pk = (unsigned*)(cursor + M);                    // [E]
    int* rank    = (int*)(pk + E);                             // [E]
    int* blocksums = rank + E;                                 // [1024]
    float2* za = (float2*)(blocksums + 1024);                  // [M]
    float2* zb = za + M;                                       // [M]
    const size_t need = 2 * (size_t)M * NHID * 2 + ((size_t)2 * M + 1) * 4
                      + (size_t)E * 8 + 1024 * 4 + (size_t)M * 2 * 8;

    if (ws_size >= need && M <= 65535) {
        unsigned short* F1 = (unsigned short*)d_out;          // 256 KB frag buffer
        float* WP = (float*)((char*)d_out + (size_t)NFEAT * NHID * 2);  // 4 KB
        float4* y4 = (float4*)hB;

        const int span = (M + 7) / 8;
        const int nb = (M + 1023) / 1024;
        const int g = (M + 63) / 64;
        const int g1 = g / 2;
        const int g2 = g - g1;
        const int CSRB = 1024;

        const int zt = NFEAT * NHID + NHID * 4 + M;
        prep_all<<<(zt + 255) / 256, blk, 0, stream>>>(W1, W2, Wlin, F1, WP, cursor, M);

        // ---- K2: gemm1 rows [0, g1*64) + hist_rank ----
        fused_g1_histrank<<<g1 + CSRB, blk, 0, stream>>>(x, F1, hA, M, g1, dst, cursor, rank, E);
        // ---- scan: local scan, then fused sums+finalize ----
        scan_local<<<nb, 1024, 0, stream>>>(cursor, offsets, blocksums, M);
        scan_fin2<<<(M + 255) / 256, blk, 0, stream>>>(offsets, blocksums, nb, M, E);
        // ---- K6: gemm1 rows [g1*64, M) + rank_sort (no atomics) ----
        fused_g1_ranksort<<<g2 + CSRB, blk, 0, stream>>>(x, F1, hA, M, g2, g1,
                                                         src, dst, ew, offsets, rank, pk, E, span);
        // ---- gather1 + relu + WP projection -> y4 ----
        gather1_proj<<<(M + 3) / 4, blk, 0, stream>>>(hA, offsets, pk, WP, y4, M);
        // ---- tiny layer-2 aggregation ----
        gather2_small<<<(M + 15) / 16, blk, 0, stream>>>(y4, offsets, pk, za, zb, M);
        // ---- Decode ----
        decode_pairs<<<(P + 255) / 256, blk, 0, stream>>>(za, zb, pei, pei + P, (float2*)out, P);
    } else {
        // fp32 atomic fallback
        float* bufA = (float*)d_ws;
        float* bufB = bufA + (size_t)M * NHID;
        const size_t zbytes = (size_t)M * NHID * sizeof(float);
        dim3 gemm_grid((M + 63) / 64, NHID / 64);
        gemm_tiled<false><<<gemm_grid, blk, 0, stream>>>(x, W1, bufA, M, NHID, NFEAT);
        hipMemsetAsync(bufB, 0, zbytes, stream);
        scatter_conv<<<2048, blk, 0, stream>>>(bufA, src, dst, ew, bufB, E);
        gemm_tiled<true><<<gemm_grid, blk, 0, stream>>>(bufB, W2, bufA, M, NHID, NHID);
        hipMemsetAsync(bufB, 0, zbytes, stream);
        scatter_conv<<<2048, blk, 0, stream>>>(bufA, src, dst, ew, bufB, E);
        decode_f<<<(P + 3) / 4, blk, 0, stream>>>(bufB, pei, pei + P, Wlin, out, P);
    }
}

// Round 21
// 174.316 us; speedup vs baseline: 1.0277x; 1.0277x over previous
//
#include <hip/hip_runtime.h>

#define NHID 256
#define NFEAT 512

using short8  = __attribute__((ext_vector_type(8))) short;
using float8  = __attribute__((ext_vector_type(8))) float;
using f32x4   = __attribute__((ext_vector_type(4))) float;

__device__ __forceinline__ float b2f(unsigned short u) {
    union { float f; unsigned v; } c;
    c.v = ((unsigned)u) << 16;
    return c.f;
}
__device__ __forceinline__ unsigned short f2b(float f) {
    union { float f; unsigned u; } c;
    c.f = f;
    unsigned r = c.u + 0x7fffu + ((c.u >> 16) & 1u);  // RNE
    return (unsigned short)(r >> 16);
}
__device__ __forceinline__ unsigned short f2h(float f) {
    union { _Float16 h; unsigned short u; } c;
    c.h = (_Float16)f;
    return c.u;
}
__device__ __forceinline__ float h2f(unsigned short u) {
    union { _Float16 h; unsigned short u; } c;
    c.u = u;
    return (float)c.h;
}

// async global->LDS, 16 B/lane; lds base wave-uniform, gsrc per-lane.
__device__ __forceinline__ void gload16(const void* gsrc, void* lds) {
    __builtin_amdgcn_global_load_lds((const __attribute__((address_space(1))) unsigned int*)gsrc,
                                     (__attribute__((address_space(3))) unsigned int*)lds,
                                     16, 0, 0);
}

// ---------------- prep: W1 -> MFMA frags, WP = W2 @ [Wlin_top|Wlin_bot], cursor zero ----------------
__global__ __launch_bounds__(256) void prep_all(const float* __restrict__ W1,
                                                const float* __restrict__ W2,
                                                const float* __restrict__ Wlin,
                                                unsigned short* __restrict__ F1,
                                                float* __restrict__ WP,
                                                int* __restrict__ cursor, int M) {
    int i = blockIdx.x * blockDim.x + threadIdx.x;
    const int T1 = NFEAT * NHID;   // 131072
    if (i < T1) {
        int j = i & 7, l = (i >> 3) & 63, cb = (i >> 9) & 15, t = i >> 13;
        int n = cb * 16 + (l & 15);
        int k = t * 32 + ((l >> 4) << 3) + j;
        F1[i] = f2b(W1[k * NHID + n]);
    } else if (i < T1 + NHID * 4) {
        int i3 = i - T1;
        int k = i3 >> 2, j = i3 & 3;
        const int base = (j >= 2) ? NHID : 0;
        const int col = j & 1;
        float acc = 0.f;
        for (int n = 0; n < NHID; ++n)
            acc += W2[k * NHID + n] * Wlin[(base + n) * 2 + col];
        WP[k * 4 + j] = acc;
    } else {
        int j = i - T1 - NHID * 4;
        if (j < M) cursor[j] = 0;
    }
}

// ---------------- GEMM1 body (round-14 verified): fp32 A via gload+swizzle, B frag regs ----------------
__device__ __forceinline__ void gemm1_body(const float* __restrict__ x,
                                           const unsigned short* __restrict__ F1,
                                           unsigned short* __restrict__ C, int M,
                                           int brow, char* AsRaw /* 2*8192 */) {
    const int tid = threadIdx.x;
    const int lane = tid & 63;
    const int wc = tid >> 6;
    const int lrow = lane & 15;
    const int lq = lane >> 4;
    const int nt = NFEAT / 32;   // 16

    int ar0 = brow + wc * 16 + (lane >> 3);
    int ar1 = ar0 + 8;
    if (ar0 >= M) ar0 = M - 1;
    if (ar1 >= M) ar1 = M - 1;
    const int aswz = ((lane & 7) ^ (lane >> 3)) * 4;
    const float* ag0 = x + (size_t)ar0 * NFEAT + aswz;
    const float* ag1 = x + (size_t)ar1 * NFEAT + aswz;
    const unsigned short* bsrc = F1 + (wc * 4) * 512 + lane * 8;

    f32x4 acc[4][4] = {};

    gload16(ag0, AsRaw + wc * 2048);
    gload16(ag1, AsRaw + wc * 2048 + 1024);
    short8 bc0 = *(const short8*)(bsrc + 0 * 512);
    short8 bc1 = *(const short8*)(bsrc + 1 * 512);
    short8 bc2 = *(const short8*)(bsrc + 2 * 512);
    short8 bc3 = *(const short8*)(bsrc + 3 * 512);
    __syncthreads();

    int p = 0;
#pragma unroll
    for (int t = 0; t < 16; ++t) {
        short8 bn0, bn1, bn2, bn3;
        if (t + 1 < nt) {
            gload16(ag0 + (t + 1) * 32, AsRaw + (p ^ 1) * 8192 + wc * 2048);
            gload16(ag1 + (t + 1) * 32, AsRaw + (p ^ 1) * 8192 + wc * 2048 + 1024);
            const unsigned short* bs_ = bsrc + (t + 1) * 8192;
            bn0 = *(const short8*)(bs_ + 0 * 512);
            bn1 = *(const short8*)(bs_ + 1 * 512);
            bn2 = *(const short8*)(bs_ + 2 * 512);
            bn3 = *(const short8*)(bs_ + 3 * 512);
        }
        short8 a[4];
#pragma unroll
        for (int m = 0; m < 4; ++m) {
            int row = m * 16 + lrow;
            const char* base = AsRaw + p * 8192 + row * 128;
            int sw = (row & 7) << 4;
            float4 f0 = *(const float4*)(base + ((lq * 32) ^ sw));
            float4 f1 = *(const float4*)(base + ((lq * 32 + 16) ^ sw));
            short8 v;
            v[0] = (short)f2b(f0.x); v[1] = (short)f2b(f0.y);
            v[2] = (short)f2b(f0.z); v[3] = (short)f2b(f0.w);
            v[4] = (short)f2b(f1.x); v[5] = (short)f2b(f1.y);
            v[6] = (short)f2b(f1.z); v[7] = (short)f2b(f1.w);
            a[m] = v;
        }
#pragma unroll
        for (int m = 0; m < 4; ++m) {
            acc[m][0] = __builtin_amdgcn_mfma_f32_16x16x32_bf16(a[m], bc0, acc[m][0], 0, 0, 0);
            acc[m][1] = __builtin_amdgcn_mfma_f32_16x16x32_bf16(a[m], bc1, acc[m][1], 0, 0, 0);
            acc[m][2] = __builtin_amdgcn_mfma_f32_16x16x32_bf16(a[m], bc2, acc[m][2], 0, 0, 0);
            acc[m][3] = __builtin_amdgcn_mfma_f32_16x16x32_bf16(a[m], bc3, acc[m][3], 0, 0, 0);
        }
        __syncthreads();
        p ^= 1;
        bc0 = bn0; bc1 = bn1; bc2 = bn2; bc3 = bn3;
    }

#pragma unroll
    for (int m = 0; m < 4; ++m)
#pragma unroll
        for (int r = 0; r < 4; ++r) {
            int row = brow + m * 16 + (lane >> 4) * 4 + r;
            if (row < M) {
#pragma unroll
                for (int n = 0; n < 4; ++n) {
                    int col = wc * 64 + n * 16 + (lane & 15);
                    C[(size_t)row * NHID + col] = f2b(acc[m][n][r]);
                }
            }
        }
}

// ---------------- K2: gemm1 (first half rows) + hist_rank ----------------
__global__ __launch_bounds__(256) void fused_g1_histrank(const float* __restrict__ x,
                                                         const unsigned short* __restrict__ F1,
                                                         unsigned short* __restrict__ C, int M,
                                                         int gblocks,
                                                         const int* __restrict__ dst,
                                                         int* __restrict__ counts,
                                                         int* __restrict__ rank, int E) {
    __shared__ char AsRaw[2 * 8192];
    if ((int)blockIdx.x < gblocks) {
        gemm1_body(x, F1, C, M, blockIdx.x * 64, AsRaw);
    } else {
        const int rank_b = blockIdx.x - gblocks;
        const int nrank = gridDim.x - gblocks;
        for (int e = rank_b * blockDim.x + threadIdx.x; e < E; e += nrank * blockDim.x)
            rank[e] = atomicAdd(&counts[dst[e]], 1);
    }
}

// ---------------- K6: gemm1 (second half rows) + rank_sort (no atomics) ----------------
__global__ __launch_bounds__(256) void fused_g1_ranksort(const float* __restrict__ x,
                                                         const unsigned short* __restrict__ F1,
                                                         unsigned short* __restrict__ C, int M,
                                                         int gblocks, int rowbase,
                                                         const int* __restrict__ src,
                                                         const int* __restrict__ dst,
                                                         const float* __restrict__ w,
                                                         const int* __restrict__ offsets,
                                                         const int* __restrict__ rank,
                                                         unsigned* __restrict__ pk,
                                                         int E, int span) {
    __shared__ char AsRaw[2 * 8192];
    if ((int)blockIdx.x < gblocks) {
        gemm1_body(x, F1, C, M, (rowbase + blockIdx.x) * 64, AsRaw);
    } else {
        const int rb = blockIdx.x - gblocks;
        const int nrb = gridDim.x - gblocks;
        const int g = rb & 7;
        const int r8 = rb >> 3;
        const int n8 = nrb >> 3;
        const int lo = g * span;
        const int hi = min(lo + span, M);
        for (int e = r8 * blockDim.x + threadIdx.x; e < E; e += n8 * blockDim.x) {
            int d = dst[e];
            if (d >= lo && d < hi)
                pk[offsets[d] + rank[e]] = ((unsigned)f2h(w[e]) << 16) | (unsigned)src[e];
        }
    }
}

// ---------------- scan: per-block local scan + fused (sums+finalize) ----------------
__global__ __launch_bounds__(1024) void scan_local(const int* __restrict__ counts,
                                                   int* __restrict__ local,
                                                   int* __restrict__ blocksums, int n) {
    __shared__ int s[1024];
    const int tid = threadIdx.x;
    const int idx = blockIdx.x * 1024 + tid;
    int v = (idx < n) ? counts[idx] : 0;
    s[tid] = v;
    __syncthreads();
    for (int off = 1; off < 1024; off <<= 1) {
        int t = (tid >= off) ? s[tid - off] : 0;
        __syncthreads();
        s[tid] += t;
        __syncthreads();
    }
    if (idx < n) local[idx] = s[tid] - v;
    if (tid == 1023) blocksums[blockIdx.x] = s[1023];
}

__global__ __launch_bounds__(256) void scan_fin2(int* __restrict__ offsets,
                                                 const int* __restrict__ blocksums,
                                                 int nb, int n, int total) {
    __shared__ int s[64];
    const int tid = threadIdx.x;
    if (tid < 64) s[tid] = (tid < nb) ? blocksums[tid] : 0;
    __syncthreads();
    int idx = blockIdx.x * blockDim.x + tid;
    if (idx < n) {
        int grp = idx >> 10;
        int gsum = 0;
        for (int j = 0; j < grp; ++j) gsum += s[j];
        offsets[idx] += gsum;
    }
    if (idx == 0) offsets[n] = total;
}

// ---------------- gather1 + relu + WP projection (round-19 4-deep, best measured) ----------------
__global__ __launch_bounds__(256) void gather1_proj(const unsigned short* __restrict__ h,
                                                    const int* __restrict__ offsets,
                                                    const unsigned* __restrict__ pk,
                                                    const float* __restrict__ WP,
                                                    float4* __restrict__ y4, int N) {
    const int lane = threadIdx.x & 63;
    const int wid = threadIdx.x >> 6;
    const int node = blockIdx.x * 4 + wid;
    if (node >= N) return;

    float wp[4][4];
#pragma unroll
    for (int i = 0; i < 4; ++i) {
        float4 r = ((const float4*)WP)[lane * 4 + i];
        wp[i][0] = r.x; wp[i][1] = r.y; wp[i][2] = r.z; wp[i][3] = r.w;
    }

    const int s0 = offsets[node];
    const int s1 = offsets[node + 1];
    float a0 = 0.f, a1 = 0.f, a2 = 0.f, a3 = 0.f;
    int i = s0;
    for (; i + 4 <= s1; i += 4) {
        unsigned q0 = pk[i], q1 = pk[i + 1], q2 = pk[i + 2], q3 = pk[i + 3];
        ushort4 v0 = ((const ushort4*)(h + (size_t)(q0 & 0xffffu) * NHID))[lane];
        ushort4 v1 = ((const ushort4*)(h + (size_t)(q1 & 0xffffu) * NHID))[lane];
        ushort4 v2 = ((const ushort4*)(h + (size_t)(q2 & 0xffffu) * NHID))[lane];
        ushort4 v3 = ((const ushort4*)(h + (size_t)(q3 & 0xffffu) * NHID))[lane];
        float w0 = h2f(q0 >> 16), w1 = h2f(q1 >> 16), w2 = h2f(q2 >> 16), w3 = h2f(q3 >> 16);
        a0 += w0 * b2f(v0.x) + w1 * b2f(v1.x) + w2 * b2f(v2.x) + w3 * b2f(v3.x);
        a1 += w0 * b2f(v0.y) + w1 * b2f(v1.y) + w2 * b2f(v2.y) + w3 * b2f(v3.y);
        a2 += w0 * b2f(v0.z) + w1 * b2f(v1.z) + w2 * b2f(v2.z) + w3 * b2f(v3.z);
        a3 += w0 * b2f(v0.w) + w1 * b2f(v1.w) + w2 * b2f(v2.w) + w3 * b2f(v3.w);
    }
    for (; i < s1; ++i) {
        unsigned q = pk[i];
        float ww = h2f(q >> 16);
        ushort4 v = ((const ushort4*)(h + (size_t)(q & 0xffffu) * NHID))[lane];
        a0 += ww * b2f(v.x);
        a1 += ww * b2f(v.y);
        a2 += ww * b2f(v.z);
        a3 += ww * b2f(v.w);
    }
    a0 = fmaxf(a0, 0.f); a1 = fmaxf(a1, 0.f);
    a2 = fmaxf(a2, 0.f); a3 = fmaxf(a3, 0.f);

    float t0 = a0 * wp[0][0] + a1 * wp[1][0] + a2 * wp[2][0] + a3 * wp[3][0];
    float t1 = a0 * wp[0][1] + a1 * wp[1][1] + a2 * wp[2][1] + a3 * wp[3][1];
    float t2 = a0 * wp[0][2] + a1 * wp[1][2] + a2 * wp[2][2] + a3 * wp[3][2];
    float t3 = a0 * wp[0][3] + a1 * wp[1][3] + a2 * wp[2][3] + a3 * wp[3][3];
#pragma unroll
    for (int off = 32; off > 0; off >>= 1) {
        t0 += __shfl_down(t0, off);
        t1 += __shfl_down(t1, off);
        t2 += __shfl_down(t2, off);
        t3 += __shfl_down(t3, off);
    }
    if (lane == 0) y4[node] = {t0, t1, t2, t3};
}

// ---------------- gather2 (tiny, unchanged) ----------------
__global__ __launch_bounds__(256) void gather2_small(const float4* __restrict__ y4,
                                                     const int* __restrict__ offsets,
                                                     const unsigned* __restrict__ pk,
                                                     float2* __restrict__ za,
                                                     float2* __restrict__ zb, int N) {
    const int lane = threadIdx.x & 63;
    const int wid = threadIdx.x >> 6;
    const int grp = lane >> 4;
    const int slot = lane & 15;
    const int node = blockIdx.x * 16 + wid * 4 + grp;
    if (node >= N) return;

    const int s0 = offsets[node];
    const int s1 = offsets[node + 1];
    float x0 = 0.f, x1 = 0.f, x2 = 0.f, x3 = 0.f;
    for (int i = s0 + slot; i < s1; i += 16) {
        unsigned q = pk[i];
        float ww = h2f(q >> 16);
        float4 v = y4[q & 0xffffu];
        x0 += ww * v.x; x1 += ww * v.y; x2 += ww * v.z; x3 += ww * v.w;
    }
#pragma unroll
    for (int off = 8; off > 0; off >>= 1) {
        x0 += __shfl_xor(x0, off);
        x1 += __shfl_xor(x1, off);
        x2 += __shfl_xor(x2, off);
        x3 += __shfl_xor(x3, off);
    }
    if (slot == 0) {
        za[node] = {x0, x1};
        zb[node] = {x2, x3};
    }
}

// ---------------- Decode (unchanged) ----------------
__global__ __launch_bounds__(256) void decode_pairs(const float2* __restrict__ za,
                                                    const float2* __restrict__ zb,
                                                    const int* __restrict__ ps,
                                                    const int* __restrict__ pd,
                                                    float2* __restrict__ out, int P) {
    int p = blockIdx.x * blockDim.x + threadIdx.x;
    if (p < P) {
        float2 va = za[ps[p]];
        float2 vb = zb[pd[p]];
        out[p] = {va.x + vb.x, va.y + vb.y};
    }
}

// ================= fp32 fallback path (ws too small or M > 65535) =================
template <bool RELU>
__global__ __launch_bounds__(256) void gemm_tiled(const float* __restrict__ A,
                                                  const float* __restrict__ B,
                                                  float* __restrict__ C,
                                                  int M, int N, int K) {
    __shared__ float As[16][65];
    __shared__ float Bs[16][64];
    const int block_row = blockIdx.x * 64;
    const int block_col = blockIdx.y * 64;
    const int tid = threadIdx.x;
    const int tx = tid & 15;
    const int ty = tid >> 4;
    float c[4][4] = {};
    for (int k0 = 0; k0 < K; k0 += 16) {
#pragma unroll
        for (int i = 0; i < 4; ++i) {
            int idx = tid + i * 256;
            int kk = idx & 15;
            int m = idx >> 4;
            int row = block_row + m;
            float v = 0.f;
            if (row < M) v = A[(long)row * K + k0 + kk];
            if (RELU) v = fmaxf(v, 0.f);
            As[kk][m] = v;
        }
#pragma unroll
        for (int i = 0; i < 4; ++i) {
            int idx = tid + i * 256;
            int n = idx & 63;
            int kk = idx >> 6;
            Bs[kk][n] = B[(long)(k0 + kk) * N + block_col + n];
        }
        __syncthreads();
#pragma unroll
        for (int kk = 0; kk < 16; ++kk) {
            float a[4], b[4];
#pragma unroll
            for (int i = 0; i < 4; ++i) a[i] = As[kk][ty * 4 + i];
#pragma unroll
            for (int j = 0; j < 4; ++j) b[j] = Bs[kk][tx * 4 + j];
#pragma unroll
            for (int i = 0; i < 4; ++i)
#pragma unroll
                for (int j = 0; j < 4; ++j) c[i][j] += a[i] * b[j];
        }
        __syncthreads();
    }
#pragma unroll
    for (int i = 0; i < 4; ++i) {
        int row = block_row + ty * 4 + i;
        if (row < M) {
            float* cp = C + (long)row * N + block_col + tx * 4;
#pragma unroll
            for (int j = 0; j < 4; ++j) cp[j] = c[i][j];
        }
    }
}

__global__ __launch_bounds__(256) void scatter_conv(const float* __restrict__ h,
                                                    const int* __restrict__ src,
                                                    const int* __restrict__ dst,
                                                    const float* __restrict__ w,
                                                    float* __restrict__ z, int E) {
    const int lane = threadIdx.x & 63;
    const int wid = threadIdx.x >> 6;
    const int nwaves = (gridDim.x * blockDim.x) >> 6;
    for (int e = blockIdx.x * 4 + wid; e < E; e += nwaves) {
        int s = src[e];
        int d = dst[e];
        float ww = w[e];
        float4 v = ((const float4*)(h + (long)s * NHID))[lane];
        float* zp = z + (long)d * NHID + lane * 4;
        atomicAdd(zp + 0, ww * v.x);
        atomicAdd(zp + 1, ww * v.y);
        atomicAdd(zp + 2, ww * v.z);
        atomicAdd(zp + 3, ww * v.w);
    }
}

__global__ __launch_bounds__(256) void decode_f(const float* __restrict__ z,
                                                const int* __restrict__ ps,
                                                const int* __restrict__ pd,
                                                const float* __restrict__ Wlin,
                                                float* __restrict__ out, int P) {
    const int lane = threadIdx.x & 63;
    const int wid = threadIdx.x >> 6;
    const int nwaves = (gridDim.x * blockDim.x) >> 6;
    float wa[8], wb[8];
#pragma unroll
    for (int i = 0; i < 8; ++i) {
        wa[i] = Wlin[(lane * 4) * 2 + i];
        wb[i] = Wlin[(NHID + lane * 4) * 2 + i];
    }
    for (int p = blockIdx.x * 4 + wid; p < P; p += nwaves) {
        int a = ps[p];
        int b = pd[p];
        float4 va = ((const float4*)(z + (long)a * NHID))[lane];
        float4 vb = ((const float4*)(z + (long)b * NHID))[lane];
        float acc0 = va.x * wa[0] + va.y * wa[2] + va.z * wa[4] + va.w * wa[6]
                   + vb.x * wb[0] + vb.y * wb[2] + vb.z * wb[4] + vb.w * wb[6];
        float acc1 = va.x * wa[1] + va.y * wa[3] + va.z * wa[5] + va.w * wa[7]
                   + vb.x * wb[1] + vb.y * wb[3] + vb.z * wb[5] + vb.w * wb[7];
#pragma unroll
        for (int off = 32; off > 0; off >>= 1) {
            acc0 += __shfl_down(acc0, off);
            acc1 += __shfl_down(acc1, off);
        }
        if (lane == 0) {
            out[(long)p * 2 + 0] = acc0;
            out[(long)p * 2 + 1] = acc1;
        }
    }
}

extern "C" void kernel_launch(void* const* d_in, const int* in_sizes, int n_in,
                              void* d_out, int out_size, void* d_ws, size_t ws_size,
                              hipStream_t stream) {
    (void)n_in; (void)out_size;
    const float* x    = (const float*)d_in[0];   // [M, 512]
    const int*   ei   = (const int*)d_in[1];     // [2, E]
    const float* ew   = (const float*)d_in[2];   // [E]
    const int*   pei  = (const int*)d_in[3];     // [2, P]
    const float* W1   = (const float*)d_in[4];   // [512, 256]
    const float* W2   = (const float*)d_in[5];   // [256, 256]
    const float* Wlin = (const float*)d_in[6];   // [512, 2]
    float* out = (float*)d_out;                  // [P, 2]

    const int E = in_sizes[2];
    const int P = in_sizes[3] / 2;
    const int M = in_sizes[0] / NFEAT;

    dim3 blk(256);
    const int* src = ei;
    const int* dst = ei + E;

    // workspace layout
    unsigned short* hA = (unsigned short*)d_ws;               // [M,256] bf16 (h1)
    unsigned short* hB = hA + (size_t)M * NHID;               // reused as y4 [M] float4
    int* offsets = (int*)(hB + (size_t)M * NHID);             // [M+1]
    int* cursor  = offsets + (M + 1);                          // [M] (counts)
    unsigned* pk = (unsigned*)(cursor + M);                    // [E]
    int* rank    = (int*)(pk + E);                             // [E]
    int* blocksums = rank + E;                                 // [1024]
    float2* za = (float2*)(blocksums + 1024);                  // [M]
    float2* zb = za + M;                                       // [M]
    const size_t need = 2 * (size_t)M * NHID * 2 + ((size_t)2 * M + 1) * 4
                      + (size_t)E * 8 + 1024 * 4 + (size_t)M * 2 * 8;

    if (ws_size >= need && M <= 65535) {
        unsigned short* F1 = (unsigned short*)d_out;          // 256 KB frag buffer
        float* WP = (float*)((char*)d_out + (size_t)NFEAT * NHID * 2);  // 4 KB
        float4* y4 = (float4*)hB;

        const int span = (M + 7) / 8;
        const int nb = (M + 1023) / 1024;
        const int g = (M + 63) / 64;
        const int g1 = g / 2;
        const int g2 = g - g1;
        const int CSRB = 1024;

        const int zt = NFEAT * NHID + NHID * 4 + M;
        prep_all<<<(zt + 255) / 256, blk, 0, stream>>>(W1, W2, Wlin, F1, WP, cursor, M);

        // ---- K2: gemm1 rows [0, g1*64) + hist_rank ----
        fused_g1_histrank<<<g1 + CSRB, blk, 0, stream>>>(x, F1, hA, M, g1, dst, cursor, rank, E);
        // ---- scan: local scan, then fused sums+finalize ----
        scan_local<<<nb, 1024, 0, stream>>>(cursor, offsets, blocksums, M);
        scan_fin2<<<(M + 255) / 256, blk, 0, stream>>>(offsets, blocksums, nb, M, E);
        // ---- K6: gemm1 rows [g1*64, M) + rank_sort (no atomics) ----
        fused_g1_ranksort<<<g2 + CSRB, blk, 0, stream>>>(x, F1, hA, M, g2, g1,
                                                         src, dst, ew, offsets, rank, pk, E, span);
        // ---- gather1 + relu + WP projection -> y4 ----
        gather1_proj<<<(M + 3) / 4, blk, 0, stream>>>(hA, offsets, pk, WP, y4, M);
        // ---- tiny layer-2 aggregation ----
        gather2_small<<<(M + 15) / 16, blk, 0, stream>>>(y4, offsets, pk, za, zb, M);
        // ---- Decode ----
        decode_pairs<<<(P + 255) / 256, blk, 0, stream>>>(za, zb, pei, pei + P, (float2*)out, P);
    } else {
        // fp32 atomic fallback
        float* bufA = (float*)d_ws;
        float* bufB = bufA + (size_t)M * NHID;
        const size_t zbytes = (size_t)M * NHID * sizeof(float);
        dim3 gemm_grid((M + 63) / 64, NHID / 64);
        gemm_tiled<false><<<gemm_grid, blk, 0, stream>>>(x, W1, bufA, M, NHID, NFEAT);
        hipMemsetAsync(bufB, 0, zbytes, stream);
        scatter_conv<<<2048, blk, 0, stream>>>(bufA, src, dst, ew, bufB, E);
        gemm_tiled<true><<<gemm_grid, blk, 0, stream>>>(bufB, W2, bufA, M, NHID, NHID);
        hipMemsetAsync(bufB, 0, zbytes, stream);
        scatter_conv<<<2048, blk, 0, stream>>>(bufA, src, dst, ew, bufB, E);
        decode_f<<<(P + 3) / 4, blk, 0, stream>>>(bufB, pei, pei + P, Wlin, out, P);
    }
}